// Round 6
// baseline (160.382 us; speedup 1.0000x reference)
//
#include <hip/hip_runtime.h>

// Single fused kernel. Key insight: BOTH slice_sites and addr2site_map are
// sorted over the same [0, 2^23) site-id domain, so a block that owns site
// range [g*4096,(g+1)*4096) owns a CONTIGUOUS range of a2s entries AND a
// contiguous range of slice_sites/outputs. Each block:
//   1. uniform binary searches for its a2s range [e0,e1) and slice range [p0,p1)
//   2. marks sig>0 entries into a 512 B LDS bitmap (vectorized, register-merged)
//   3. probes its own slice entries against the LDS bitmap and writes the
//      contiguous output range (vector interior + scalar edges).
// No global bitmap, no global atomics, no second pass, one launch.

typedef int   v4i __attribute__((ext_vector_type(4)));
typedef float v4f __attribute__((ext_vector_type(4)));

static constexpr int NUM_SITES_TOTAL = 2048 * 4096;            // 8,388,608
static constexpr int WORDS_PER_BLOCK = 128;                    // 512 B LDS bitmap
static constexpr int SITES_PER_BLOCK = WORDS_PER_BLOCK * 32;   // 4096 ids
static constexpr int GRID            = NUM_SITES_TOTAL / SITES_PER_BLOCK; // 2048
static constexpr int BLOCK           = 256;
static constexpr int CHUNK           = 16;  // a2s entries/thread/iter (4 x v4i)

__global__ __launch_bounds__(BLOCK) void fused_kernel(
    const int*   __restrict__ ss,
    const int*   __restrict__ sig,
    const int*   __restrict__ a2s,
    const float* __restrict__ sc,
    float*       __restrict__ rem,
    float*       __restrict__ avail,
    int n_slice, int n_clb)
{
    __shared__ unsigned int lbm[WORDS_PER_BLOCK];

    const int siteBase = blockIdx.x * SITES_PER_BLOCK;
    const int siteEnd  = siteBase + SITES_PER_BLOCK;

    for (int w = threadIdx.x; w < WORDS_PER_BLOCK; w += BLOCK) lbm[w] = 0u;

    // ---- uniform binary searches (scalar path; all operands wave-uniform) --
    int lo = 0, hi = n_clb;
    while (lo < hi) { int m = (lo + hi) >> 1; if (a2s[m] < siteBase) lo = m + 1; else hi = m; }
    const int e0 = lo;
    hi = n_clb;
    while (lo < hi) { int m = (lo + hi) >> 1; if (a2s[m] < siteEnd) lo = m + 1; else hi = m; }
    const int e1 = lo;

    lo = 0; hi = n_slice;
    while (lo < hi) { int m = (lo + hi) >> 1; if (ss[m] < siteBase) lo = m + 1; else hi = m; }
    const int p0 = lo;
    hi = n_slice;
    while (lo < hi) { int m = (lo + hi) >> 1; if (ss[m] < siteEnd) lo = m + 1; else hi = m; }
    const int p1 = lo;

    __syncthreads();

    // ---- mark phase: build LDS bitmap from a2s[e0..e1) where sig>0 ---------
    const int start = e0 & ~(CHUNK - 1);   // 16B-align vector loads; strays
                                           // fail the site-range check below
    for (int s = start + threadIdx.x * CHUNK; s < e1; s += BLOCK * CHUNK) {
        int av[CHUNK], gv[CHUNK];
        if (s + CHUNK <= n_clb) {
            const v4i* ap = (const v4i*)(a2s + s);
            const v4i* gp = (const v4i*)(sig + s);
#pragma unroll
            for (int q = 0; q < CHUNK / 4; ++q) {
                v4i a = ap[q];
                av[4*q+0] = a.x; av[4*q+1] = a.y; av[4*q+2] = a.z; av[4*q+3] = a.w;
                v4i g = gp[q];
                gv[4*q+0] = g.x; gv[4*q+1] = g.y; gv[4*q+2] = g.z; gv[4*q+3] = g.w;
            }
        } else {
#pragma unroll
            for (int j = 0; j < CHUNK; ++j) {
                const int i = s + j;
                const bool ok = i < n_clb;
                av[j] = ok ? a2s[i] : -1;
                gv[j] = ok ? sig[i] : 0;
            }
        }

        unsigned int curw = 0xFFFFFFFFu, curm = 0u;
#pragma unroll
        for (int j = 0; j < CHUNK; ++j) {
            const int site = av[j];
            if (gv[j] > 0 && site >= siteBase && site < siteEnd) {
                const unsigned int u = (unsigned int)(site - siteBase);
                const unsigned int w = u >> 5;
                const unsigned int m = 1u << (u & 31u);
                if (w == curw) curm |= m;
                else { if (curm) atomicOr(&lbm[curw], curm); curw = w; curm = m; }
            }
        }
        if (curm) atomicOr(&lbm[curw], curm);
    }

    __syncthreads();

    // ---- probe phase: slice_sites[p0..p1) -> rem/avail[p0..p1) -------------
    int i0 = (p0 + 3) & ~3;   // vector interior [i0, i1), scalar edges
    int i1 = p1 & ~3;
    if (i1 < i0) i1 = i0;

    for (int q = (i0 >> 2) + threadIdx.x; q < (i1 >> 2); q += BLOCK) {
        v4i s = __builtin_nontemporal_load((const v4i*)ss + q);
        v4f f = __builtin_nontemporal_load((const v4f*)sc + q);
        v4f r, a;
#pragma unroll
        for (int j = 0; j < 4; ++j) {
            const unsigned int u   = (unsigned int)(s[j] - siteBase);
            const unsigned int bit = (lbm[u >> 5] >> (u & 31u)) & 1u;
            r[j] = bit ? 0.0f : 1.0f;
            a[j] = bit ? 0.0f : f[j];
        }
        __builtin_nontemporal_store(r, (v4f*)rem + q);
        __builtin_nontemporal_store(a, (v4f*)avail + q);
    }
    // leading edge [p0, min(i0,p1))
    for (int i = p0 + threadIdx.x; i < min(i0, p1); i += BLOCK) {
        const unsigned int u   = (unsigned int)(ss[i] - siteBase);
        const unsigned int bit = (lbm[u >> 5] >> (u & 31u)) & 1u;
        rem[i]   = bit ? 0.0f : 1.0f;
        avail[i] = bit ? 0.0f : sc[i];
    }
    // trailing edge [max(i1,p0), p1)
    for (int i = max(i1, p0) + threadIdx.x; i < p1; i += BLOCK) {
        const unsigned int u   = (unsigned int)(ss[i] - siteBase);
        const unsigned int bit = (lbm[u >> 5] >> (u & 31u)) & 1u;
        rem[i]   = bit ? 0.0f : 1.0f;
        avail[i] = bit ? 0.0f : sc[i];
    }
}

extern "C" void kernel_launch(void* const* d_in, const int* in_sizes, int n_in,
                              void* d_out, int out_size, void* d_ws, size_t ws_size,
                              hipStream_t stream) {
    const int*   slice_sites = (const int*)d_in[0];
    const int*   sig         = (const int*)d_in[1];
    const int*   a2s         = (const int*)d_in[2];
    const float* scores      = (const float*)d_in[3];
    const int n_slice = in_sizes[0];
    const int n_clb   = in_sizes[1];

    float* rem   = (float*)d_out;
    float* avail = rem + n_slice;

    fused_kernel<<<GRID, BLOCK, 0, stream>>>(
        slice_sites, sig, a2s, scores, rem, avail, n_slice, n_clb);
}

// Round 7
// 157.538 us; speedup vs baseline: 1.0181x; 1.0181x over previous
//
#include <hip/hip_runtime.h>

// Two kernels:
//  boundary_kernel: 2049 parallel threads compute per-block partition
//    boundaries (lower_bound of g*4096 in both sorted arrays) -> d_ws.
//    Replaces 4 serially-dependent binary searches per block in the fused
//    kernel (the R6 latency bottleneck) with massively parallel ones.
//  fused_kernel: block g owns site range [g*4096,(g+1)*4096). Reads its
//    boundaries, marks sig>0 entries of its a2s slice into a 512 B LDS
//    bitmap (contiguous vec4 loads, register-merged LDS atomics), then
//    probes its contiguous slice_sites range against LDS and writes the
//    contiguous output range. Traffic = read-once + write-once.

typedef int   v4i __attribute__((ext_vector_type(4)));
typedef float v4f __attribute__((ext_vector_type(4)));

static constexpr int NUM_SITES_TOTAL = 2048 * 4096;            // 8,388,608
static constexpr int WORDS_PER_BLOCK = 128;                    // 512 B LDS bitmap
static constexpr int SITES_PER_BLOCK = WORDS_PER_BLOCK * 32;   // 4096 ids
static constexpr int GRID            = NUM_SITES_TOTAL / SITES_PER_BLOCK; // 2048
static constexpr int BLOCK           = 256;

__global__ __launch_bounds__(BLOCK) void boundary_kernel(
    const int* __restrict__ ss, const int* __restrict__ a2s,
    int* __restrict__ eb, int* __restrict__ pb, int n_slice, int n_clb)
{
    const int g = blockIdx.x * BLOCK + threadIdx.x;
    if (g > GRID) return;
    const int key = g * SITES_PER_BLOCK;   // g==GRID -> key = 2^23 > all ids

    int lo = 0, hi = n_clb;
    while (lo < hi) { int m = (lo + hi) >> 1; if (a2s[m] < key) lo = m + 1; else hi = m; }
    eb[g] = lo;

    lo = 0; hi = n_slice;
    while (lo < hi) { int m = (lo + hi) >> 1; if (ss[m] < key) lo = m + 1; else hi = m; }
    pb[g] = lo;
}

__global__ __launch_bounds__(BLOCK) void fused_kernel(
    const int*   __restrict__ ss,
    const int*   __restrict__ sig,
    const int*   __restrict__ a2s,
    const float* __restrict__ sc,
    const int*   __restrict__ eb,
    const int*   __restrict__ pb,
    float*       __restrict__ rem,
    float*       __restrict__ avail,
    int n_clb)
{
    __shared__ unsigned int lbm[WORDS_PER_BLOCK];

    const int g        = blockIdx.x;
    const int siteBase = g * SITES_PER_BLOCK;
    const int siteEnd  = siteBase + SITES_PER_BLOCK;

    for (int w = threadIdx.x; w < WORDS_PER_BLOCK; w += BLOCK) lbm[w] = 0u;

    const int e0 = eb[g], e1 = eb[g + 1];
    const int p0 = pb[g], p1 = pb[g + 1];

    __syncthreads();

    // ---- mark phase: a2s[e0..e1), sig>0 -> LDS bitmap ----------------------
    // Thread handles 4 consecutive entries (one v4i each of a2s/sig):
    // fully coalesced 16 B/lane. Edge entries outside [siteBase,siteEnd)
    // fail the range check (they belong to neighbor blocks).
    const int mstart = e0 & ~3;
    for (int s = mstart + threadIdx.x * 4; s < e1; s += BLOCK * 4) {
        int av[4], gv[4];
        if (s + 4 <= n_clb) {
            v4i a = __builtin_nontemporal_load((const v4i*)(a2s + s));
            v4i gg = __builtin_nontemporal_load((const v4i*)(sig + s));
            av[0]=a.x; av[1]=a.y; av[2]=a.z; av[3]=a.w;
            gv[0]=gg.x; gv[1]=gg.y; gv[2]=gg.z; gv[3]=gg.w;
        } else {
#pragma unroll
            for (int j = 0; j < 4; ++j) {
                const int i = s + j;
                const bool ok = i < n_clb;
                av[j] = ok ? a2s[i] : -1;
                gv[j] = ok ? sig[i] : 0;
            }
        }
        unsigned int curw = 0xFFFFFFFFu, curm = 0u;
#pragma unroll
        for (int j = 0; j < 4; ++j) {
            const int site = av[j];
            if (gv[j] > 0 && site >= siteBase && site < siteEnd) {
                const unsigned int u = (unsigned int)(site - siteBase);
                const unsigned int w = u >> 5;
                const unsigned int m = 1u << (u & 31u);
                if (w == curw) curm |= m;
                else { if (curm) atomicOr(&lbm[curw], curm); curw = w; curm = m; }
            }
        }
        if (curm) atomicOr(&lbm[curw], curm);
    }

    __syncthreads();

    // ---- probe phase: slice_sites[p0..p1) -> rem/avail[p0..p1) -------------
    int i0 = (p0 + 3) & ~3;   // vector interior [i0,i1), scalar edges
    int i1 = p1 & ~3;
    if (i1 < i0) i1 = i0;

    for (int q = (i0 >> 2) + threadIdx.x; q < (i1 >> 2); q += BLOCK) {
        v4i s = __builtin_nontemporal_load((const v4i*)ss + q);
        v4f f = __builtin_nontemporal_load((const v4f*)sc + q);
        v4f r, a;
#pragma unroll
        for (int j = 0; j < 4; ++j) {
            const unsigned int u   = (unsigned int)(s[j] - siteBase);
            const unsigned int bit = (lbm[u >> 5] >> (u & 31u)) & 1u;
            r[j] = bit ? 0.0f : 1.0f;
            a[j] = bit ? 0.0f : f[j];
        }
        __builtin_nontemporal_store(r, (v4f*)rem + q);
        __builtin_nontemporal_store(a, (v4f*)avail + q);
    }
    for (int i = p0 + threadIdx.x; i < min(i0, p1); i += BLOCK) {
        const unsigned int u   = (unsigned int)(ss[i] - siteBase);
        const unsigned int bit = (lbm[u >> 5] >> (u & 31u)) & 1u;
        rem[i]   = bit ? 0.0f : 1.0f;
        avail[i] = bit ? 0.0f : sc[i];
    }
    for (int i = max(i1, p0) + threadIdx.x; i < p1; i += BLOCK) {
        const unsigned int u   = (unsigned int)(ss[i] - siteBase);
        const unsigned int bit = (lbm[u >> 5] >> (u & 31u)) & 1u;
        rem[i]   = bit ? 0.0f : 1.0f;
        avail[i] = bit ? 0.0f : sc[i];
    }
}

extern "C" void kernel_launch(void* const* d_in, const int* in_sizes, int n_in,
                              void* d_out, int out_size, void* d_ws, size_t ws_size,
                              hipStream_t stream) {
    const int*   slice_sites = (const int*)d_in[0];
    const int*   sig         = (const int*)d_in[1];
    const int*   a2s         = (const int*)d_in[2];
    const float* scores      = (const float*)d_in[3];
    const int n_slice = in_sizes[0];
    const int n_clb   = in_sizes[1];

    int* eb = (int*)d_ws;          // GRID+1 ints
    int* pb = eb + (GRID + 1);     // GRID+1 ints

    boundary_kernel<<<(GRID + 1 + BLOCK - 1) / BLOCK, BLOCK, 0, stream>>>(
        slice_sites, a2s, eb, pb, n_slice, n_clb);

    float* rem   = (float*)d_out;
    float* avail = rem + n_slice;

    fused_kernel<<<GRID, BLOCK, 0, stream>>>(
        slice_sites, sig, a2s, scores, eb, pb, rem, avail, n_clb);
}

// Round 8
// 150.005 us; speedup vs baseline: 1.0692x; 1.0502x over previous
//
#include <hip/hip_runtime.h>

// Three-phase, zero-binary-search design. site ids live in [0, 2^23); bin =
// site >> 12 (4096 ids per bin, 2048 bins). Both slice_sites and addr2site_map
// are sorted, so the per-bin partition boundaries of each array are exactly
// the indices where bin(x[i-1]) != bin(x[i]): one streaming pass finds ALL
// 2x2049 boundaries with coalesced vec4 loads and no dependent-load chains
// (the R7 boundary kernel burned ~17us on cold binary-search pointer chases).
// The fused kernel then: marks its a2s slice into a 512B LDS bitmap
// (register-merged LDS atomics), probes its contiguous slice_sites range,
// and writes the contiguous output range. Traffic ~ read-once+write-once.

typedef int   v4i __attribute__((ext_vector_type(4)));
typedef float v4f __attribute__((ext_vector_type(4)));

static constexpr int WORDS_PER_BLOCK = 128;            // 512 B LDS bitmap
static constexpr int SITES_PER_BLOCK = 4096;           // = 2^BIN_SHIFT
static constexpr int BIN_SHIFT       = 12;
static constexpr int GRID            = 2048;           // bins
static constexpr int BLOCK           = 256;

// ---- boundary detection by bin transitions (sorted input) ------------------
__device__ __forceinline__ void transitions(
    const int* __restrict__ x, int* __restrict__ bnd, int n, int t)
{
    const int s = t * 4;
    if (s >= n) return;
    int v[4];
    int cnt;
    if (s + 4 <= n) {
        v4i a = __builtin_nontemporal_load((const v4i*)(x + s));
        v[0] = a.x; v[1] = a.y; v[2] = a.z; v[3] = a.w;
        cnt = 4;
    } else {
        cnt = n - s;
        for (int j = 0; j < cnt; ++j) v[j] = x[s + j];
    }
    int pbin = (s == 0) ? -1 : (x[s - 1] >> BIN_SHIFT);  // line already in L1
    for (int j = 0; j < cnt; ++j) {
        const int i = s + j;
        const int cbin = v[j] >> BIN_SHIFT;
        for (int b = pbin + 1; b <= cbin; ++b) bnd[b] = i;  // ~1 write / 2929 elems
        if (i == n - 1)
            for (int b = cbin + 1; b <= GRID; ++b) bnd[b] = n;
        pbin = cbin;
    }
}

__global__ __launch_bounds__(BLOCK) void bounds_kernel(
    const int* __restrict__ ss, const int* __restrict__ a2s,
    int* __restrict__ pb, int* __restrict__ eb, int n_slice, int n_clb)
{
    const int t = blockIdx.x * BLOCK + threadIdx.x;
    transitions(ss,  pb, n_slice, t);
    transitions(a2s, eb, n_clb,  t);
}

// ---- fused mark + probe per bin --------------------------------------------
__global__ __launch_bounds__(BLOCK) void fused_kernel(
    const int*   __restrict__ ss,
    const int*   __restrict__ sig,
    const int*   __restrict__ a2s,
    const float* __restrict__ sc,
    const int*   __restrict__ eb,
    const int*   __restrict__ pb,
    float*       __restrict__ rem,
    float*       __restrict__ avail,
    int n_clb)
{
    __shared__ unsigned int lbm[WORDS_PER_BLOCK];

    const int g        = blockIdx.x;
    const int siteBase = g * SITES_PER_BLOCK;
    const int siteEnd  = siteBase + SITES_PER_BLOCK;

    for (int w = threadIdx.x; w < WORDS_PER_BLOCK; w += BLOCK) lbm[w] = 0u;

    const int e0 = eb[g], e1 = eb[g + 1];
    const int p0 = pb[g], p1 = pb[g + 1];

    __syncthreads();

    // mark: 8 entries/thread (4 NT vec4 loads in flight). Edge entries outside
    // [siteBase,siteEnd) fail the range check (they belong to neighbor bins).
    const int mstart = e0 & ~3;   // 16B-align both vec4s (stride 8 keeps s%4==0)
    for (int s = mstart + threadIdx.x * 8; s < e1; s += BLOCK * 8) {
        int av[8], gv[8];
        if (s + 8 <= n_clb) {
            v4i a0 = __builtin_nontemporal_load((const v4i*)(a2s + s));
            v4i a1 = __builtin_nontemporal_load((const v4i*)(a2s + s + 4));
            v4i g0 = __builtin_nontemporal_load((const v4i*)(sig + s));
            v4i g1 = __builtin_nontemporal_load((const v4i*)(sig + s + 4));
            av[0]=a0.x; av[1]=a0.y; av[2]=a0.z; av[3]=a0.w;
            av[4]=a1.x; av[5]=a1.y; av[6]=a1.z; av[7]=a1.w;
            gv[0]=g0.x; gv[1]=g0.y; gv[2]=g0.z; gv[3]=g0.w;
            gv[4]=g1.x; gv[5]=g1.y; gv[6]=g1.z; gv[7]=g1.w;
        } else {
#pragma unroll
            for (int j = 0; j < 8; ++j) {
                const int i = s + j;
                const bool ok = i < n_clb;
                av[j] = ok ? a2s[i] : -1;
                gv[j] = ok ? sig[i] : 0;
            }
        }
        unsigned int curw = 0xFFFFFFFFu, curm = 0u;
#pragma unroll
        for (int j = 0; j < 8; ++j) {
            const int site = av[j];
            if (gv[j] > 0 && site >= siteBase && site < siteEnd) {
                const unsigned int u = (unsigned int)(site - siteBase);
                const unsigned int w = u >> 5;
                const unsigned int m = 1u << (u & 31u);
                if (w == curw) curm |= m;
                else { if (curm) atomicOr(&lbm[curw], curm); curw = w; curm = m; }
            }
        }
        if (curm) atomicOr(&lbm[curw], curm);
    }

    __syncthreads();

    // probe: slice_sites[p0..p1) -> rem/avail[p0..p1); vector interior + edges
    int i0 = (p0 + 3) & ~3;
    int i1 = p1 & ~3;
    if (i1 < i0) i1 = i0;

    for (int q = (i0 >> 2) + threadIdx.x; q < (i1 >> 2); q += BLOCK) {
        v4i s = __builtin_nontemporal_load((const v4i*)ss + q);
        v4f f = __builtin_nontemporal_load((const v4f*)sc + q);
        v4f r, a;
#pragma unroll
        for (int j = 0; j < 4; ++j) {
            const unsigned int u   = (unsigned int)(s[j] - siteBase);
            const unsigned int bit = (lbm[u >> 5] >> (u & 31u)) & 1u;
            r[j] = bit ? 0.0f : 1.0f;
            a[j] = bit ? 0.0f : f[j];
        }
        __builtin_nontemporal_store(r, (v4f*)rem + q);
        __builtin_nontemporal_store(a, (v4f*)avail + q);
    }
    for (int i = p0 + threadIdx.x; i < min(i0, p1); i += BLOCK) {
        const unsigned int u   = (unsigned int)(ss[i] - siteBase);
        const unsigned int bit = (lbm[u >> 5] >> (u & 31u)) & 1u;
        rem[i]   = bit ? 0.0f : 1.0f;
        avail[i] = bit ? 0.0f : sc[i];
    }
    for (int i = max(i1, p0) + threadIdx.x; i < p1; i += BLOCK) {
        const unsigned int u   = (unsigned int)(ss[i] - siteBase);
        const unsigned int bit = (lbm[u >> 5] >> (u & 31u)) & 1u;
        rem[i]   = bit ? 0.0f : 1.0f;
        avail[i] = bit ? 0.0f : sc[i];
    }
}

extern "C" void kernel_launch(void* const* d_in, const int* in_sizes, int n_in,
                              void* d_out, int out_size, void* d_ws, size_t ws_size,
                              hipStream_t stream) {
    const int*   slice_sites = (const int*)d_in[0];
    const int*   sig         = (const int*)d_in[1];
    const int*   a2s         = (const int*)d_in[2];
    const float* scores      = (const float*)d_in[3];
    const int n_slice = in_sizes[0];
    const int n_clb   = in_sizes[1];

    int* eb = (int*)d_ws;          // GRID+1 ints
    int* pb = eb + (GRID + 1);     // GRID+1 ints

    const int n_max = n_slice > n_clb ? n_slice : n_clb;
    const int tblocks = (n_max / 4 + BLOCK - 1) / BLOCK + 1;
    bounds_kernel<<<tblocks, BLOCK, 0, stream>>>(
        slice_sites, a2s, pb, eb, n_slice, n_clb);

    float* rem   = (float*)d_out;
    float* avail = rem + n_slice;

    fused_kernel<<<GRID, BLOCK, 0, stream>>>(
        slice_sites, sig, a2s, scores, eb, pb, rem, avail, n_clb);
}